// Round 2
// baseline (777.456 us; speedup 1.0000x reference)
//
#include <hip/hip_runtime.h>

// Sparsity_Checker: fused passthrough-copy + collector histogram + finalize.
// All four reference outputs derive from the 5-bin histogram of
// collector = sum_t spikes[t] (values 0..T):
//   unique_counts[k]  = hist[k]
//   coll_zero_frac    = hist[0] / total
//   sparsity_ratio    = (total*T - sum_k k*hist[k]) / (total*T)
// Single read of input + single write of output = 411 MB floor (memory-bound).
//
// R2: REVERT nontemporal hints (R1 lesson: __builtin_nontemporal_* on gfx950
// demoted the stream to a slow path — 600 GB/s, 5.4x regression. Plain cached
// float4 accesses hit ~4.3 TB/s). Keep grid=2048 (8 blocks/CU, confirmed
// occupancy 55%) and keep finalize fused into the last block.

constexpr int T_STEPS = 4;

__global__ __launch_bounds__(256) void spike_stats_kernel(
    const float4* __restrict__ in, float4* __restrict__ out,
    unsigned int* __restrict__ ws, float* __restrict__ tail,
    int nvec, double total)
{
    unsigned int* hist = ws;        // [5] bins
    unsigned int* done = ws + 5;    // completion counter

    __shared__ unsigned int lhist[5];
    __shared__ bool amLast;
    if (threadIdx.x < 5) lhist[threadIdx.x] = 0u;
    if (threadIdx.x == 0) amLast = false;
    __syncthreads();

    // packed histogram: 5 bins x 12 bits. Per-wave bin max at grid=2048x256:
    // 64 lanes * 4 elems * ceil(3211264/524288)=7 iters = 1792 < 4096.
    unsigned long long packed = 0ull;

    const int stride = gridDim.x * blockDim.x;
    for (int v = blockIdx.x * blockDim.x + threadIdx.x; v < nvec; v += stride) {
        float4 a0 = in[0 * nvec + v];
        float4 a1 = in[1 * nvec + v];
        float4 a2 = in[2 * nvec + v];
        float4 a3 = in[3 * nvec + v];
        out[0 * nvec + v] = a0;
        out[1 * nvec + v] = a1;
        out[2 * nvec + v] = a2;
        out[3 * nvec + v] = a3;
        // elements are exactly 0.0f or 1.0f -> sums are exact small ints
        int cx = (int)(a0.x + a1.x + a2.x + a3.x);
        int cy = (int)(a0.y + a1.y + a2.y + a3.y);
        int cz = (int)(a0.z + a1.z + a2.z + a3.z);
        int cw = (int)(a0.w + a1.w + a2.w + a3.w);
        packed += (1ull << (cx * 12)) + (1ull << (cy * 12))
                + (1ull << (cz * 12)) + (1ull << (cw * 12));
    }

    // wave-64 butterfly reduce of the packed histogram
#pragma unroll
    for (int off = 32; off > 0; off >>= 1)
        packed += __shfl_down(packed, off, 64);

    if ((threadIdx.x & 63) == 0) {
#pragma unroll
        for (int k = 0; k < 5; ++k)
            atomicAdd(&lhist[k], (unsigned int)((packed >> (12 * k)) & 0xFFFull));
    }
    __syncthreads();

    // 5 global atomics per block (2048 blocks) — negligible contention
    if (threadIdx.x < 5)
        atomicAdd(&hist[threadIdx.x], lhist[threadIdx.x]);

    __threadfence();
    if (threadIdx.x == 0) {
        unsigned int prev = __hip_atomic_fetch_add(
            done, 1u, __ATOMIC_ACQ_REL, __HIP_MEMORY_SCOPE_AGENT);
        amLast = (prev == gridDim.x - 1);
    }
    __syncthreads();

    // last block finalizes the scalar tail (replaces separate finalize kernel)
    if (amLast && threadIdx.x == 0) {
        unsigned int h[5];
        double spikes_sum = 0.0;
#pragma unroll
        for (int k = 0; k < 5; ++k) {
            h[k] = __hip_atomic_load(&hist[k], __ATOMIC_RELAXED,
                                     __HIP_MEMORY_SCOPE_AGENT);
            spikes_sum += (double)k * (double)h[k];
        }
        double denom = total * (double)T_STEPS;
        tail[0] = (float)((denom - spikes_sum) / denom); // sparsity_ratio
        tail[1] = (float)((double)h[0] / total);         // coll_zero_frac
#pragma unroll
        for (int k = 0; k < 5; ++k)
            tail[2 + k] = (float)h[k];                   // unique_counts (< 2^24, exact)
    }
}

extern "C" void kernel_launch(void* const* d_in, const int* in_sizes, int n_in,
                              void* d_out, int out_size, void* d_ws, size_t ws_size,
                              hipStream_t stream)
{
    const float* spikes = (const float*)d_in[0];
    float* out = (float*)d_out;

    const long n = (long)in_sizes[0];       // T*B*C*H*W = 51,380,224
    const long per_t = n / T_STEPS;         // 12,845,056 elements per timestep
    const int nvec = (int)(per_t / 4);      // 3,211,264 float4 per timestep

    unsigned int* ws = (unsigned int*)d_ws; // hist[5] + done counter
    hipMemsetAsync(d_ws, 0, 6 * sizeof(unsigned int), stream);

    spike_stats_kernel<<<dim3(2048), dim3(256), 0, stream>>>(
        (const float4*)spikes, (float4*)out, ws, out + n, nvec, (double)per_t);
}

// Round 4
// 418.527 us; speedup vs baseline: 1.8576x; 1.8576x over previous
//
#include <hip/hip_runtime.h>

// Sparsity_Checker — R4: re-run of the R3 bisect (R3 died to container infra,
// no data). R1/R2 regressed the stats kernel ~95us -> ~550us; NT hints ruled
// out (R2). Suspects: (a) fused finalize w/ agent-scope fence, (b) grid
// 1024->2048, (c) container/environment.
// Plan: EXACT R0 baseline (A: grid 1024 + separate finalize, known 349.5us
// config) plus one extra idempotent dispatch B, same kernel symbol launched
// at grid 2048 with its own hist region. rocprof reports both dispatches
// separately -> same-container A/B isolates grid vs fence vs environment.
// (vs R3: single non-templated kernel symbol, grid via gridDim — removes the
// dual-template-instantiation variable, learn_hip rule #19.)

constexpr int T_STEPS = 4;

__global__ __launch_bounds__(256) void spike_stats_kernel(
    const float4* __restrict__ in, float4* __restrict__ out,
    unsigned int* __restrict__ hist, int nvec)
{
    __shared__ unsigned int lhist[5];
    if (threadIdx.x < 5) lhist[threadIdx.x] = 0u;
    __syncthreads();

    // packed histogram: 5 bins x 12 bits. Per-wave bin max:
    //   grid=1024: 64 lanes * 4 elems * 13 iters = 3328 < 4096
    //   grid=2048: 64 lanes * 4 elems *  7 iters = 1792 < 4096
    unsigned long long packed = 0ull;

    const int stride = gridDim.x * blockDim.x;
    for (int v = blockIdx.x * blockDim.x + threadIdx.x; v < nvec; v += stride) {
        float4 a0 = in[0 * nvec + v];
        float4 a1 = in[1 * nvec + v];
        float4 a2 = in[2 * nvec + v];
        float4 a3 = in[3 * nvec + v];
        out[0 * nvec + v] = a0;
        out[1 * nvec + v] = a1;
        out[2 * nvec + v] = a2;
        out[3 * nvec + v] = a3;
        // elements are exactly 0.0f or 1.0f -> sums are exact small ints
        int cx = (int)(a0.x + a1.x + a2.x + a3.x);
        int cy = (int)(a0.y + a1.y + a2.y + a3.y);
        int cz = (int)(a0.z + a1.z + a2.z + a3.z);
        int cw = (int)(a0.w + a1.w + a2.w + a3.w);
        packed += (1ull << (cx * 12)) + (1ull << (cy * 12))
                + (1ull << (cz * 12)) + (1ull << (cw * 12));
    }

    // wave-64 butterfly reduce of the packed histogram
#pragma unroll
    for (int off = 32; off > 0; off >>= 1)
        packed += __shfl_down(packed, off, 64);

    if ((threadIdx.x & 63) == 0) {
#pragma unroll
        for (int k = 0; k < 5; ++k)
            atomicAdd(&lhist[k], (unsigned int)((packed >> (12 * k)) & 0xFFFull));
    }
    __syncthreads();

    if (threadIdx.x < 5)
        atomicAdd(&hist[threadIdx.x], lhist[threadIdx.x]);
}

__global__ void finalize_kernel(const unsigned int* __restrict__ hist,
                                float* __restrict__ tail, double total)
{
    if (threadIdx.x == 0 && blockIdx.x == 0) {
        double spikes_sum = 0.0;
#pragma unroll
        for (int k = 0; k < 5; ++k)
            spikes_sum += (double)k * (double)hist[k];
        double denom = total * (double)T_STEPS;
        tail[0] = (float)((denom - spikes_sum) / denom); // sparsity_ratio
        tail[1] = (float)((double)hist[0] / total);      // coll_zero_frac
#pragma unroll
        for (int k = 0; k < 5; ++k)
            tail[2 + k] = (float)hist[k];                // unique_counts (exact: < 2^24)
    }
}

extern "C" void kernel_launch(void* const* d_in, const int* in_sizes, int n_in,
                              void* d_out, int out_size, void* d_ws, size_t ws_size,
                              hipStream_t stream)
{
    const float* spikes = (const float*)d_in[0];
    float* out = (float*)d_out;

    const long n = (long)in_sizes[0];       // T*B*C*H*W = 51,380,224
    const long per_t = n / T_STEPS;         // 12,845,056 elements per timestep
    const int nvec = (int)(per_t / 4);      // 3,211,264 float4 per timestep

    unsigned int* ws = (unsigned int*)d_ws; // [0..4] hist A, [8..12] hist B
    hipMemsetAsync(d_ws, 0, 16 * sizeof(unsigned int), stream);

    // A: exact R0 baseline config (known-good 349.5us total)
    spike_stats_kernel<<<dim3(1024), dim3(256), 0, stream>>>(
        (const float4*)spikes, (float4*)out, ws, nvec);

    // B: same kernel symbol, grid 2048, separate hist — output rewrite is
    // idempotent; hist B unused. Pure A/B probe dispatch.
    spike_stats_kernel<<<dim3(2048), dim3(256), 0, stream>>>(
        (const float4*)spikes, (float4*)out, ws + 8, nvec);

    finalize_kernel<<<dim3(1), dim3(64), 0, stream>>>(ws, out + n, (double)per_t);
}

// Round 5
// 344.316 us; speedup vs baseline: 2.2580x; 1.2155x over previous
//
#include <hip/hip_runtime.h>

// Sparsity_Checker: passthrough-copy + collector histogram (+tiny finalize).
// All four reference outputs derive from the 5-bin histogram of
// collector = sum_t spikes[t] (values 0..T):
//   unique_counts[k]  = hist[k]
//   coll_zero_frac    = hist[0] / total
//   sparsity_ratio    = (total*T - sum_k k*hist[k]) / (total*T)
// Single read of input + single write of output = 411 MB floor (memory-bound).
//
// Session ledger:
//  R0  349.5us  grid 1024 + separate finalize (stats ~95us inferred)
//  R1  766.7us  NT hints + fused finalize w/ fence + grid 2048  -> 513us stats
//  R2  777.5us  fence + grid 2048 (NT reverted)                 -> 547us stats
//  R4  418.5us  bisect: A(1024, no fence) + B(2048, no fence) both fast;
//               B ~= 69us. Grid exonerated; cliff was the per-block
//               __threadfence (agent-scope L2 writeback x2048 blocks)
//               and/or preloaded-container state. Remedy: NEVER fence in
//               the streaming kernel; finalize stays a separate dispatch.
//  R5  (this)   single stats dispatch = B's exact config: grid 2048,
//               no fence, separate finalize.

constexpr int T_STEPS = 4;

__global__ __launch_bounds__(256) void spike_stats_kernel(
    const float4* __restrict__ in, float4* __restrict__ out,
    unsigned int* __restrict__ hist, int nvec)
{
    __shared__ unsigned int lhist[5];
    if (threadIdx.x < 5) lhist[threadIdx.x] = 0u;
    __syncthreads();

    // packed histogram: 5 bins x 12 bits. Per-wave bin max at grid=2048x256:
    // 64 lanes * 4 elems * ceil(3211264/524288)=7 iters = 1792 < 4096.
    unsigned long long packed = 0ull;

    const int stride = gridDim.x * blockDim.x;
    for (int v = blockIdx.x * blockDim.x + threadIdx.x; v < nvec; v += stride) {
        float4 a0 = in[0 * nvec + v];
        float4 a1 = in[1 * nvec + v];
        float4 a2 = in[2 * nvec + v];
        float4 a3 = in[3 * nvec + v];
        out[0 * nvec + v] = a0;
        out[1 * nvec + v] = a1;
        out[2 * nvec + v] = a2;
        out[3 * nvec + v] = a3;
        // elements are exactly 0.0f or 1.0f -> sums are exact small ints
        int cx = (int)(a0.x + a1.x + a2.x + a3.x);
        int cy = (int)(a0.y + a1.y + a2.y + a3.y);
        int cz = (int)(a0.z + a1.z + a2.z + a3.z);
        int cw = (int)(a0.w + a1.w + a2.w + a3.w);
        packed += (1ull << (cx * 12)) + (1ull << (cy * 12))
                + (1ull << (cz * 12)) + (1ull << (cw * 12));
    }

    // wave-64 butterfly reduce of the packed histogram
#pragma unroll
    for (int off = 32; off > 0; off >>= 1)
        packed += __shfl_down(packed, off, 64);

    if ((threadIdx.x & 63) == 0) {
#pragma unroll
        for (int k = 0; k < 5; ++k)
            atomicAdd(&lhist[k], (unsigned int)((packed >> (12 * k)) & 0xFFFull));
    }
    __syncthreads();

    // 5 global atomics per block (2048 blocks) — negligible contention
    if (threadIdx.x < 5)
        atomicAdd(&hist[threadIdx.x], lhist[threadIdx.x]);
}

__global__ void finalize_kernel(const unsigned int* __restrict__ hist,
                                float* __restrict__ tail, double total)
{
    if (threadIdx.x == 0 && blockIdx.x == 0) {
        double spikes_sum = 0.0;
#pragma unroll
        for (int k = 0; k < 5; ++k)
            spikes_sum += (double)k * (double)hist[k];
        double denom = total * (double)T_STEPS;
        tail[0] = (float)((denom - spikes_sum) / denom); // sparsity_ratio
        tail[1] = (float)((double)hist[0] / total);      // coll_zero_frac
#pragma unroll
        for (int k = 0; k < 5; ++k)
            tail[2 + k] = (float)hist[k];                // unique_counts (exact: < 2^24)
    }
}

extern "C" void kernel_launch(void* const* d_in, const int* in_sizes, int n_in,
                              void* d_out, int out_size, void* d_ws, size_t ws_size,
                              hipStream_t stream)
{
    const float* spikes = (const float*)d_in[0];
    float* out = (float*)d_out;

    const long n = (long)in_sizes[0];       // T*B*C*H*W = 51,380,224
    const long per_t = n / T_STEPS;         // 12,845,056 elements per timestep
    const int nvec = (int)(per_t / 4);      // 3,211,264 float4 per timestep

    unsigned int* hist = (unsigned int*)d_ws;
    hipMemsetAsync(d_ws, 0, 8 * sizeof(unsigned int), stream);

    spike_stats_kernel<<<dim3(2048), dim3(256), 0, stream>>>(
        (const float4*)spikes, (float4*)out, hist, nvec);

    finalize_kernel<<<dim3(1), dim3(64), 0, stream>>>(hist, out + n, (double)per_t);
}